// Round 9
// baseline (175.938 us; speedup 1.0000x reference)
//
#include <hip/hip_runtime.h>
#include <hip/hip_bf16.h>

#define MSEQ 2048

typedef __attribute__((ext_vector_type(8))) short short8;
typedef __attribute__((ext_vector_type(4))) float f32x4;

static __device__ __forceinline__ short bf16b(float f) {
    __hip_bfloat16 h = __float2bfloat16(f);   // RNE
    return *reinterpret_cast<short*>(&h);
}

// pack 2 fp32 -> 2 bf16 (RNE, single v_cvt_pk_bf16_f32 on gfx950)
static __device__ __forceinline__ unsigned int pk2(float a, float b) {
    float2 f2; f2.x = a; f2.y = b;
    __hip_bfloat162 p = __float22bfloat162_rn(f2);
    return *reinterpret_cast<unsigned int*>(&p);
}

// async global->LDS, 16B per lane; LDS dest = wave-uniform base + lane*16
static __device__ __forceinline__ void gl_lds16(const void* g, void* l) {
    __builtin_amdgcn_global_load_lds(
        (const __attribute__((address_space(1))) unsigned int*)g,
        (__attribute__((address_space(3))) unsigned int*)l, 16, 0, 0);
}

// ---------------- W -> WT[n][k] bf16 (n: 0..127 Wq | 128..255 Wk | 256..767 Wv) ----------------
__global__ __launch_bounds__(256) void wtrans_kernel(
    const float* __restrict__ Wq, const float* __restrict__ Wk,
    const float* __restrict__ Wv, unsigned short* __restrict__ WT)
{
    const int nt = blockIdx.x;   // 12 tiles of 64 n
    const int kt = blockIdx.y;   // 8 tiles of 64 k
    const int t  = threadIdx.x;
    const int k0 = kt*64;

    const float* W; int ld, n0;
    if (nt < 2)      { W = Wq; ld = 128; n0 = nt*64; }
    else if (nt < 4) { W = Wk; ld = 128; n0 = (nt-2)*64; }
    else             { W = Wv; ld = 512; n0 = (nt-4)*64; }

    __shared__ unsigned short Ts[64*72];   // [n][k]

    #pragma unroll
    for (int s = 0; s < 4; ++s) {
        const int lin = s*256 + t;
        const int krow = lin >> 4, ng = lin & 15;
        const float4 v = *(const float4*)(W + (size_t)(k0+krow)*ld + n0 + ng*4);
        Ts[(ng*4+0)*72 + krow] = (unsigned short)bf16b(v.x);
        Ts[(ng*4+1)*72 + krow] = (unsigned short)bf16b(v.y);
        Ts[(ng*4+2)*72 + krow] = (unsigned short)bf16b(v.z);
        Ts[(ng*4+3)*72 + krow] = (unsigned short)bf16b(v.w);
    }
    __syncthreads();
    #pragma unroll
    for (int s = 0; s < 2; ++s) {
        const int lin = s*256 + t;
        const int nrow = lin >> 3, kg = lin & 7;
        *(short8*)(WT + (size_t)(nt*64 + nrow)*512 + k0 + kg*8) = *(const short8*)&Ts[nrow*72 + kg*8];
    }
}

// ---------------- Fused projection GEMM, bf16 MFMA ----------------
// [Qh|Kh|Vf] = x @ WT^T + bias.  M-tile 64 -> grid 6x128 = 768 blocks = 3/CU
// exactly balanced (round-8's 384-block grid left 25%+ idle).  x read fp32,
// converted in-register during A-staging; B via gl_lds16.
__global__ __launch_bounds__(256, 4) void proj_mfma(
    const float* __restrict__ x, const unsigned short* __restrict__ WT,
    const float* __restrict__ bq, const float* __restrict__ bk, const float* __restrict__ bv,
    unsigned short* __restrict__ Qh, unsigned short* __restrict__ Kh, unsigned short* __restrict__ Vf)
{
    const int nt = blockIdx.x;        // 0..5 (0=Q,1=K,2..5=V)
    const int r0 = blockIdx.y * 64;   // m (keys)
    const int n0 = nt * 128;
    const int t = threadIdx.x, w = t >> 6, lane = t & 63, l15 = lane & 15, quad = lane >> 4;
    const int wqh = w >> 1, wch = w & 1;

    __shared__ short smem[128*72];    // 18432 B; As/Bs alias front, Ts uses all
    short* As = smem;                 // [64 m][32 k]
    short* Bs = smem + 64*32;         // [128 n][32 k]

    f32x4 acc[2][4];
    #pragma unroll
    for (int i = 0; i < 2; ++i)
        #pragma unroll
        for (int j = 0; j < 4; ++j) acc[i][j] = {0.f,0.f,0.f,0.f};

    const int brow = lane >> 2, bkg = lane & 3;

    for (int kk = 0; kk < 512; kk += 32) {
        // B staging (bf16, async direct-to-LDS): 128 rows x 32 k
        #pragma unroll
        for (int s = 0; s < 2; ++s)
            gl_lds16(WT + (size_t)(n0 + w*32 + s*16 + brow)*512 + kk + bkg*8,
                     Bs + (w*32 + s*16)*32);
        // A staging: 64 rows x 32 k fp32 -> bf16 in-register, b64 LDS writes
        #pragma unroll
        for (int s = 0; s < 2; ++s) {
            const int idx = s*256 + t;
            const int row = idx >> 3, cg = idx & 7;
            const float4 v = *(const float4*)(x + (size_t)(r0+row)*512 + kk + cg*4);
            uint2 uu; uu.x = pk2(v.x, v.y); uu.y = pk2(v.z, v.w);
            *(uint2*)&As[row*32 + cg*4] = uu;
        }
        __syncthreads();
        short8 Af[2], Bf[4];
        #pragma unroll
        for (int i = 0; i < 2; ++i) Af[i] = *(const short8*)&As[(wqh*32 + i*16 + l15)*32 + quad*8];
        #pragma unroll
        for (int j = 0; j < 4; ++j) Bf[j] = *(const short8*)&Bs[(wch*64 + j*16 + l15)*32 + quad*8];
        #pragma unroll
        for (int i = 0; i < 2; ++i)
            #pragma unroll
            for (int j = 0; j < 4; ++j)
                acc[i][j] = __builtin_amdgcn_mfma_f32_16x16x32_bf16(Af[i], Bf[j], acc[i][j], 0, 0, 0);
        __syncthreads();
    }

    const float* bias = (nt == 0) ? bq : (nt == 1) ? bk : (bv + (nt-2)*128);
    float bj[4];
    #pragma unroll
    for (int j = 0; j < 4; ++j) bj[j] = bias[wch*64 + j*16 + l15];

    const int b = r0 >> 11, key0 = r0 & 2047;
    if (nt < 2) {
        short* Ts = smem;   // [64][136]
        #pragma unroll
        for (int i = 0; i < 2; ++i)
            #pragma unroll
            for (int j = 0; j < 4; ++j)
                #pragma unroll
                for (int r = 0; r < 4; ++r)
                    Ts[(wqh*32 + i*16 + quad*4 + r)*136 + wch*64 + j*16 + l15] =
                        bf16b(acc[i][j][r] + bj[j]);
        __syncthreads();
        unsigned short* Out = (nt == 0) ? Qh : Kh;
        #pragma unroll
        for (int s = 0; s < 4; ++s) {
            const int lin = s*256 + t, row = lin >> 4, seg = lin & 15;
            const int h = seg >> 1, dh = seg & 1;
            *(short8*)(Out + ((size_t)(b*8 + h)*MSEQ + key0 + row)*16 + dh*8) =
                *(const short8*)&Ts[row*136 + seg*8];
        }
    } else {
        short* Ts = smem;   // [128 ch][72], key-major inner
        #pragma unroll
        for (int i = 0; i < 2; ++i)
            #pragma unroll
            for (int j = 0; j < 4; ++j)
                #pragma unroll
                for (int r = 0; r < 4; ++r)
                    Ts[(wch*64 + j*16 + l15)*72 + wqh*32 + i*16 + quad*4 + r] =
                        bf16b(acc[i][j][r] + bj[j]);
        __syncthreads();
        const int kt0 = key0 >> 6, h0 = (nt-2)*2;
        #pragma unroll
        for (int s = 0; s < 4; ++s) {
            const int lin = s*256 + t;
            const int lane_ = lin & 63, kh = (lin>>6)&1, ci = (lin>>7)&1;
            const int chh = (lin>>8)&1, h_l = (lin>>9)&1;
            const int l15_ = lane_ & 15, quad_ = lane_ >> 4;
            const int ch_local  = h_l*64 + (chh*2+ci)*16 + l15_;
            const int key_local = kh*32 + quad_*8;
            const size_t addr = (((((size_t)(b*8 + h0 + h_l)*32 + kt0)*2 + chh)*2 + ci)*2 + kh)*512
                                + lane_*8;
            *(short8*)(Vf + addr) = *(const short8*)&Ts[ch_local*72 + key_local];
        }
    }
}

// ---------------- Fused masked attention, bf16 MFMA, register-pipelined ----------------
// S^T = K.Q^T; Q/K head-interleaved, V fragment-order (coalesced global).
// K/mask/V for tile kt+1 PREFETCHED into registers before tile kt's exp phase
// -> global latency hides under compute instead of sitting on the barrier path.
__global__ __launch_bounds__(256, 4) void attn_mfma(
    const unsigned short* __restrict__ Qh, const unsigned short* __restrict__ Kh,
    const unsigned short* __restrict__ Vf, const int* __restrict__ mask,
    const float* __restrict__ gamma, float* __restrict__ out)
{
    const int m0 = blockIdx.x * 64;   // q tile
    const int bh = blockIdx.y;
    const int b  = bh >> 3, h = bh & 7;
    const int t  = threadIdx.x;
    const int wave = t >> 6, lane = t & 63, l15 = lane & 15, quad = lane >> 4;
    const int qh = wave >> 1, chh = wave & 1;

    __shared__ short Ws[2*64*68];     // [q][key] double-buffered, stride 68
    __shared__ float wsl[4*64];
    __shared__ float wsums[64];

    const short8 zz = {0,0,0,0,0,0,0,0};

    const unsigned short* Qrow = Qh + (size_t)(b*8 + h)*MSEQ*16;
    const unsigned short* Krow = Kh + (size_t)(b*8 + h)*MSEQ*16;
    const unsigned short* Vbh  = Vf + (size_t)(b*8 + h)*32*4096;
    const int* mrow = mask + b*MSEQ + wave*16 + quad*4;

    // Q B-fragments (once per block): B[k=d][n=q], quads 2/3 = zero pad (K=16->32)
    short8 qfrag[4];
    #pragma unroll
    for (int c = 0; c < 4; ++c)
        qfrag[c] = (quad < 2)
            ? *(const short8*)(Qrow + (size_t)(m0 + c*16 + l15)*16 + quad*8)
            : zz;

    f32x4 acc[2][2] = {{{0.f,0.f,0.f,0.f},{0.f,0.f,0.f,0.f}},
                       {{0.f,0.f,0.f,0.f},{0.f,0.f,0.f,0.f}}};
    float wsum_acc[4] = {0.f,0.f,0.f,0.f};

    // ---- prefetch tile 0 ----
    short8 kfrag_n = (quad < 2)
        ? *(const short8*)(Krow + (size_t)(wave*16 + l15)*16 + quad*8) : zz;
    int4 mi_n = *(const int4*)(mrow);
    short8 Bfn[2][2];
    #pragma unroll
    for (int ci = 0; ci < 2; ++ci)
        #pragma unroll
        for (int kh = 0; kh < 2; ++kh)
            Bfn[ci][kh] = *(const short8*)(Vbh + (size_t)(((chh*2 + ci)*2 + kh))*512 + lane*8);

    for (int kt = 0; kt < 32; ++kt) {
        short* Wp = Ws + (kt & 1)*64*68;
        const short8 kfrag = kfrag_n;
        const int4 mi = mi_n;
        short8 Bf[2][2];
        #pragma unroll
        for (int ci = 0; ci < 2; ++ci)
            #pragma unroll
            for (int kh = 0; kh < 2; ++kh) Bf[ci][kh] = Bfn[ci][kh];

        // ---- prefetch tile kt+1 (hides under the exp phase + barrier) ----
        if (kt < 31) {
            const int kn1 = (kt+1)*64;
            kfrag_n = (quad < 2)
                ? *(const short8*)(Krow + (size_t)(kn1 + wave*16 + l15)*16 + quad*8) : zz;
            mi_n = *(const int4*)(mrow + kn1);
            #pragma unroll
            for (int ci = 0; ci < 2; ++ci)
                #pragma unroll
                for (int kh = 0; kh < 2; ++kh)
                    Bfn[ci][kh] = *(const short8*)(Vbh
                        + (size_t)((((kt+1)*2 + chh)*2 + ci)*2 + kh)*512 + lane*8);
        }

        const float mk[4] = {(float)mi.x, (float)mi.y, (float)mi.z, (float)mi.w};

        // ---- scores S^T -> weights ----
        #pragma unroll
        for (int c = 0; c < 4; ++c) {
            f32x4 s = {0.f,0.f,0.f,0.f};
            s = __builtin_amdgcn_mfma_f32_16x16x32_bf16(kfrag, qfrag[c], s, 0, 0, 0);
            float w0 = mk[0] * __expf(fmaxf(0.25f*s[0], 0.f));
            float w1 = mk[1] * __expf(fmaxf(0.25f*s[1], 0.f));
            float w2 = mk[2] * __expf(fmaxf(0.25f*s[2], 0.f));
            float w3 = mk[3] * __expf(fmaxf(0.25f*s[3], 0.f));
            uint2 uu; uu.x = pk2(w0, w1); uu.y = pk2(w2, w3);
            *(uint2*)&Wp[(c*16 + l15)*68 + wave*16 + quad*4] = uu;
            wsum_acc[c] += (w0 + w1) + (w2 + w3);
        }

        __syncthreads();

        // ---- PV: wave quadrant rows qh*32..+31, chs chh*32..+31 ----
        short8 Af[2][2];
        #pragma unroll
        for (int si = 0; si < 2; ++si)
            #pragma unroll
            for (int kh = 0; kh < 2; ++kh)
                Af[si][kh] = *(const short8*)&Wp[((qh*2+si)*16 + l15)*68 + kh*32 + quad*8];
        #pragma unroll
        for (int si = 0; si < 2; ++si)
            #pragma unroll
            for (int ci = 0; ci < 2; ++ci)
                #pragma unroll
                for (int kh = 0; kh < 2; ++kh)
                    acc[si][ci] = __builtin_amdgcn_mfma_f32_16x16x32_bf16(
                        Af[si][kh], Bf[ci][kh], acc[si][ci], 0, 0, 0);
        // no second barrier: next tile writes the OTHER Ws buffer
    }

    // ---- wsum reduction (once) ----
    #pragma unroll
    for (int c = 0; c < 4; ++c) {
        float v = wsum_acc[c];
        v += __shfl_xor(v, 16, 64);
        v += __shfl_xor(v, 32, 64);
        if (quad == 0) wsl[wave*64 + c*16 + l15] = v;
    }
    __syncthreads();
    if (t < 64) wsums[t] = (wsl[t] + wsl[64+t]) + (wsl[128+t] + wsl[192+t]);
    __syncthreads();

    const float g = gamma[0];
    #pragma unroll
    for (int si = 0; si < 2; ++si) {
        #pragma unroll
        for (int r = 0; r < 4; ++r) {
            const int row = qh*32 + si*16 + quad*4 + r;
            const float inv = g / fmaxf(wsums[row], 1e-20f);
            #pragma unroll
            for (int ci = 0; ci < 2; ++ci) {
                const int col = chh*32 + ci*16 + l15;
                out[(size_t)(b*MSEQ + m0 + row)*512 + h*64 + col] = acc[si][ci][r] * inv;
            }
        }
    }
}

extern "C" void kernel_launch(void* const* d_in, const int* in_sizes, int n_in,
                              void* d_out, int out_size, void* d_ws, size_t ws_size,
                              hipStream_t stream) {
    const float* x     = (const float*)d_in[0];
    const int*   mask  = (const int*)  d_in[1];
    const float* Wq    = (const float*)d_in[2];
    const float* bq    = (const float*)d_in[3];
    const float* Wk    = (const float*)d_in[4];
    const float* bk    = (const float*)d_in[5];
    const float* Wv    = (const float*)d_in[6];
    const float* bv    = (const float*)d_in[7];
    const float* gamma = (const float*)d_in[8];
    float* outp = (float*)d_out;

    // ws (bf16 shorts): WT 0.75MB | Qh 2MB | Kh 2MB | Vf 8MB
    unsigned short* WT = (unsigned short*)d_ws;
    unsigned short* Qh = WT + (size_t)768*512;
    unsigned short* Kh = Qh + (size_t)8192*128;
    unsigned short* Vf = Kh + (size_t)8192*128;

    wtrans_kernel<<<dim3(12, 8), 256, 0, stream>>>(Wq, Wk, Wv, WT);
    proj_mfma<<<dim3(6, 128), 256, 0, stream>>>(x, WT, bq, bk, bv, Qh, Kh, Vf);
    attn_mfma<<<dim3(32, 32), 256, 0, stream>>>(Qh, Kh, Vf, mask, gamma, outp);
}

// Round 10
// 173.739 us; speedup vs baseline: 1.0127x; 1.0127x over previous
//
#include <hip/hip_runtime.h>
#include <hip/hip_bf16.h>

#define MSEQ 2048

typedef __attribute__((ext_vector_type(8))) short short8;
typedef __attribute__((ext_vector_type(4))) float f32x4;

static __device__ __forceinline__ short bf16b(float f) {
    __hip_bfloat16 h = __float2bfloat16(f);   // RNE
    return *reinterpret_cast<short*>(&h);
}

// pack 2 fp32 -> 2 bf16 (RNE, single v_cvt_pk_bf16_f32 on gfx950)
static __device__ __forceinline__ unsigned int pk2(float a, float b) {
    float2 f2; f2.x = a; f2.y = b;
    __hip_bfloat162 p = __float22bfloat162_rn(f2);
    return *reinterpret_cast<unsigned int*>(&p);
}

// async global->LDS, 16B per lane; LDS dest = wave-uniform base + lane*16
static __device__ __forceinline__ void gl_lds16(const void* g, void* l) {
    __builtin_amdgcn_global_load_lds(
        (const __attribute__((address_space(1))) unsigned int*)g,
        (__attribute__((address_space(3))) unsigned int*)l, 16, 0, 0);
}

// ---------------- W -> WT[n][k] bf16 (n: 0..127 Wq | 128..255 Wk | 256..767 Wv) ----------------
__global__ __launch_bounds__(256) void wtrans_kernel(
    const float* __restrict__ Wq, const float* __restrict__ Wk,
    const float* __restrict__ Wv, unsigned short* __restrict__ WT)
{
    const int nt = blockIdx.x;   // 12 tiles of 64 n
    const int kt = blockIdx.y;   // 8 tiles of 64 k
    const int t  = threadIdx.x;
    const int k0 = kt*64;

    const float* W; int ld, n0;
    if (nt < 2)      { W = Wq; ld = 128; n0 = nt*64; }
    else if (nt < 4) { W = Wk; ld = 128; n0 = (nt-2)*64; }
    else             { W = Wv; ld = 512; n0 = (nt-4)*64; }

    __shared__ unsigned short Ts[64*72];   // [n][k]

    #pragma unroll
    for (int s = 0; s < 4; ++s) {
        const int lin = s*256 + t;
        const int krow = lin >> 4, ng = lin & 15;
        const float4 v = *(const float4*)(W + (size_t)(k0+krow)*ld + n0 + ng*4);
        Ts[(ng*4+0)*72 + krow] = (unsigned short)bf16b(v.x);
        Ts[(ng*4+1)*72 + krow] = (unsigned short)bf16b(v.y);
        Ts[(ng*4+2)*72 + krow] = (unsigned short)bf16b(v.z);
        Ts[(ng*4+3)*72 + krow] = (unsigned short)bf16b(v.w);
    }
    __syncthreads();
    #pragma unroll
    for (int s = 0; s < 2; ++s) {
        const int lin = s*256 + t;
        const int nrow = lin >> 3, kg = lin & 7;
        *(short8*)(WT + (size_t)(nt*64 + nrow)*512 + k0 + kg*8) = *(const short8*)&Ts[nrow*72 + kg*8];
    }
}

// ---------------- Fused projection GEMM, bf16 MFMA ----------------
// [Qh|Kh|Vf] = x @ WT^T + bias.  M-tile 64 -> grid 6x128 = 768 blocks = 3/CU
// balanced.  x read fp32, converted in-register during A-staging; B via gl_lds16.
__global__ __launch_bounds__(256, 4) void proj_mfma(
    const float* __restrict__ x, const unsigned short* __restrict__ WT,
    const float* __restrict__ bq, const float* __restrict__ bk, const float* __restrict__ bv,
    unsigned short* __restrict__ Qh, unsigned short* __restrict__ Kh, unsigned short* __restrict__ Vf)
{
    const int nt = blockIdx.x;        // 0..5 (0=Q,1=K,2..5=V)
    const int r0 = blockIdx.y * 64;   // m (keys)
    const int n0 = nt * 128;
    const int t = threadIdx.x, w = t >> 6, lane = t & 63, l15 = lane & 15, quad = lane >> 4;
    const int wqh = w >> 1, wch = w & 1;

    __shared__ short smem[128*72];    // 18432 B; As/Bs alias front, Ts uses all
    short* As = smem;                 // [64 m][32 k]
    short* Bs = smem + 64*32;         // [128 n][32 k]

    f32x4 acc[2][4];
    #pragma unroll
    for (int i = 0; i < 2; ++i)
        #pragma unroll
        for (int j = 0; j < 4; ++j) acc[i][j] = {0.f,0.f,0.f,0.f};

    const int brow = lane >> 2, bkg = lane & 3;

    for (int kk = 0; kk < 512; kk += 32) {
        #pragma unroll
        for (int s = 0; s < 2; ++s)
            gl_lds16(WT + (size_t)(n0 + w*32 + s*16 + brow)*512 + kk + bkg*8,
                     Bs + (w*32 + s*16)*32);
        #pragma unroll
        for (int s = 0; s < 2; ++s) {
            const int idx = s*256 + t;
            const int row = idx >> 3, cg = idx & 7;
            const float4 v = *(const float4*)(x + (size_t)(r0+row)*512 + kk + cg*4);
            uint2 uu; uu.x = pk2(v.x, v.y); uu.y = pk2(v.z, v.w);
            *(uint2*)&As[row*32 + cg*4] = uu;
        }
        __syncthreads();
        short8 Af[2], Bf[4];
        #pragma unroll
        for (int i = 0; i < 2; ++i) Af[i] = *(const short8*)&As[(wqh*32 + i*16 + l15)*32 + quad*8];
        #pragma unroll
        for (int j = 0; j < 4; ++j) Bf[j] = *(const short8*)&Bs[(wch*64 + j*16 + l15)*32 + quad*8];
        #pragma unroll
        for (int i = 0; i < 2; ++i)
            #pragma unroll
            for (int j = 0; j < 4; ++j)
                acc[i][j] = __builtin_amdgcn_mfma_f32_16x16x32_bf16(Af[i], Bf[j], acc[i][j], 0, 0, 0);
        __syncthreads();
    }

    const float* bias = (nt == 0) ? bq : (nt == 1) ? bk : (bv + (nt-2)*128);
    float bj[4];
    #pragma unroll
    for (int j = 0; j < 4; ++j) bj[j] = bias[wch*64 + j*16 + l15];

    const int b = r0 >> 11, key0 = r0 & 2047;
    if (nt < 2) {
        short* Ts = smem;   // [64][136]
        #pragma unroll
        for (int i = 0; i < 2; ++i)
            #pragma unroll
            for (int j = 0; j < 4; ++j)
                #pragma unroll
                for (int r = 0; r < 4; ++r)
                    Ts[(wqh*32 + i*16 + quad*4 + r)*136 + wch*64 + j*16 + l15] =
                        bf16b(acc[i][j][r] + bj[j]);
        __syncthreads();
        unsigned short* Out = (nt == 0) ? Qh : Kh;
        #pragma unroll
        for (int s = 0; s < 4; ++s) {
            const int lin = s*256 + t, row = lin >> 4, seg = lin & 15;
            const int h = seg >> 1, dh = seg & 1;
            *(short8*)(Out + ((size_t)(b*8 + h)*MSEQ + key0 + row)*16 + dh*8) =
                *(const short8*)&Ts[row*136 + seg*8];
        }
    } else {
        short* Ts = smem;   // [128 ch][72], key-major inner
        #pragma unroll
        for (int i = 0; i < 2; ++i)
            #pragma unroll
            for (int j = 0; j < 4; ++j)
                #pragma unroll
                for (int r = 0; r < 4; ++r)
                    Ts[(wch*64 + j*16 + l15)*72 + wqh*32 + i*16 + quad*4 + r] =
                        bf16b(acc[i][j][r] + bj[j]);
        __syncthreads();
        const int kt0 = key0 >> 6, h0 = (nt-2)*2;
        #pragma unroll
        for (int s = 0; s < 4; ++s) {
            const int lin = s*256 + t;
            const int lane_ = lin & 63, kh = (lin>>6)&1, ci = (lin>>7)&1;
            const int chh = (lin>>8)&1, h_l = (lin>>9)&1;
            const int l15_ = lane_ & 15, quad_ = lane_ >> 4;
            const int ch_local  = h_l*64 + (chh*2+ci)*16 + l15_;
            const int key_local = kh*32 + quad_*8;
            const size_t addr = (((((size_t)(b*8 + h0 + h_l)*32 + kt0)*2 + chh)*2 + ci)*2 + kh)*512
                                + lane_*8;
            *(short8*)(Vf + addr) = *(const short8*)&Ts[ch_local*72 + key_local];
        }
    }
}

// ---------------- Fused masked attention: producer/consumer wave specialization ----------------
// Block = 512 threads. Waves 0-3 PRODUCE scores (S^T = K.Q^T, exp, mask, W->LDS,
// wsum partials); waves 4-7 CONSUME (PV MFMA on the previous tile's W + direct
// fragment-order V loads). One uniform barrier/tile; Ws parity double-buffer.
// Exp+MFMA pipes co-schedule across waves (m114) -> per-tile = max, not sum.
__global__ __launch_bounds__(512, 4) void attn_mfma(
    const unsigned short* __restrict__ Qh, const unsigned short* __restrict__ Kh,
    const unsigned short* __restrict__ Vf, const int* __restrict__ mask,
    const float* __restrict__ gamma, float* __restrict__ out)
{
    const int m0 = blockIdx.x * 64;   // q tile
    const int bh = blockIdx.y;
    const int b  = bh >> 3, h = bh & 7;
    const int t  = threadIdx.x;
    const int wave = t >> 6, lane = t & 63, l15 = lane & 15, quad = lane >> 4;

    __shared__ short Ws[2*64*68];     // [q][key] parity double-buffered, stride 68
    __shared__ float wsl[4*64];
    __shared__ float wsums[64];

    const short8 zz = {0,0,0,0,0,0,0,0};
    constexpr float SC = 0.25f * 1.44269504f;   // 1/sqrt(16) folded into exp2 scale

    // ---- producer state (waves 0-3) ----
    short8 qfrag[4];
    short8 kfrag_n = zz;
    int4 mi_n = {0,0,0,0};
    float wsum_acc[4] = {0.f,0.f,0.f,0.f};
    const unsigned short* Krow = Kh + (size_t)(b*8 + h)*MSEQ*16;
    const int* mrow = mask + b*MSEQ + wave*16 + quad*4;

    // ---- consumer state (waves 4-7) ----
    const int w4 = wave & 3;
    const int qh = w4 >> 1, chh = w4 & 1;
    const unsigned short* Vbh = Vf + (size_t)(b*8 + h)*32*4096;
    f32x4 acc[2][2] = {{{0.f,0.f,0.f,0.f},{0.f,0.f,0.f,0.f}},
                       {{0.f,0.f,0.f,0.f},{0.f,0.f,0.f,0.f}}};

    if (wave < 4) {
        const unsigned short* Qrow = Qh + (size_t)(b*8 + h)*MSEQ*16;
        #pragma unroll
        for (int c = 0; c < 4; ++c)
            qfrag[c] = (quad < 2)
                ? *(const short8*)(Qrow + (size_t)(m0 + c*16 + l15)*16 + quad*8)
                : zz;
        kfrag_n = (quad < 2)
            ? *(const short8*)(Krow + (size_t)(wave*16 + l15)*16 + quad*8) : zz;
        mi_n = *(const int4*)(mrow);
    }

    for (int kt = 0; kt <= 32; ++kt) {
        if (wave < 4) {
            if (kt < 32) {
                const short8 kfrag = kfrag_n;
                const int4 mi = mi_n;
                if (kt < 31) {   // register prefetch of next K-frag + mask
                    kfrag_n = (quad < 2)
                        ? *(const short8*)(Krow + (size_t)((kt+1)*64 + wave*16 + l15)*16 + quad*8)
                        : zz;
                    mi_n = *(const int4*)(mrow + (kt+1)*64);
                }
                short* Wp = Ws + (kt & 1)*64*68;
                #pragma unroll
                for (int c = 0; c < 4; ++c) {
                    f32x4 s = {0.f,0.f,0.f,0.f};
                    s = __builtin_amdgcn_mfma_f32_16x16x32_bf16(kfrag, qfrag[c], s, 0, 0, 0);
                    const float e0 = __builtin_amdgcn_exp2f(fmaxf(SC*s[0], 0.f));
                    const float e1 = __builtin_amdgcn_exp2f(fmaxf(SC*s[1], 0.f));
                    const float e2 = __builtin_amdgcn_exp2f(fmaxf(SC*s[2], 0.f));
                    const float e3 = __builtin_amdgcn_exp2f(fmaxf(SC*s[3], 0.f));
                    const float w0 = mi.x ? e0 : 0.f;
                    const float w1 = mi.y ? e1 : 0.f;
                    const float w2 = mi.z ? e2 : 0.f;
                    const float w3 = mi.w ? e3 : 0.f;
                    uint2 uu; uu.x = pk2(w0, w1); uu.y = pk2(w2, w3);
                    *(uint2*)&Wp[(c*16 + l15)*68 + wave*16 + quad*4] = uu;
                    wsum_acc[c] += (w0 + w1) + (w2 + w3);
                }
            }
        } else {
            if (kt >= 1) {
                const int j = kt - 1;
                // V B-fragments: coalesced fragment-order loads; consumer slack
                // (producers are the bottleneck) absorbs the latency.
                short8 Bf[2][2];
                #pragma unroll
                for (int ci = 0; ci < 2; ++ci)
                    #pragma unroll
                    for (int kh = 0; kh < 2; ++kh)
                        Bf[ci][kh] = *(const short8*)(Vbh
                            + (size_t)(((j*2 + chh)*2 + ci)*2 + kh)*512 + lane*8);
                const short* Wp = Ws + (j & 1)*64*68;
                short8 Af[2][2];
                #pragma unroll
                for (int si = 0; si < 2; ++si)
                    #pragma unroll
                    for (int kh = 0; kh < 2; ++kh)
                        Af[si][kh] = *(const short8*)&Wp[((qh*2+si)*16 + l15)*68 + kh*32 + quad*8];
                #pragma unroll
                for (int si = 0; si < 2; ++si)
                    #pragma unroll
                    for (int ci = 0; ci < 2; ++ci)
                        #pragma unroll
                        for (int kh = 0; kh < 2; ++kh)
                            acc[si][ci] = __builtin_amdgcn_mfma_f32_16x16x32_bf16(
                                Af[si][kh], Bf[ci][kh], acc[si][ci], 0, 0, 0);
            }
        }
        __syncthreads();
    }

    // ---- wsum reduction (producers) ----
    if (wave < 4) {
        #pragma unroll
        for (int c = 0; c < 4; ++c) {
            float v = wsum_acc[c];
            v += __shfl_xor(v, 16, 64);
            v += __shfl_xor(v, 32, 64);
            if (quad == 0) wsl[wave*64 + c*16 + l15] = v;
        }
    }
    __syncthreads();
    if (t < 64) wsums[t] = (wsl[t] + wsl[64+t]) + (wsl[128+t] + wsl[192+t]);
    __syncthreads();

    // ---- epilogue (consumers) ----
    if (wave >= 4) {
        const float g = gamma[0];
        #pragma unroll
        for (int si = 0; si < 2; ++si) {
            #pragma unroll
            for (int r = 0; r < 4; ++r) {
                const int row = qh*32 + si*16 + quad*4 + r;
                const float inv = g / fmaxf(wsums[row], 1e-20f);
                #pragma unroll
                for (int ci = 0; ci < 2; ++ci) {
                    const int col = chh*32 + ci*16 + l15;
                    out[(size_t)(b*MSEQ + m0 + row)*512 + h*64 + col] = acc[si][ci][r] * inv;
                }
            }
        }
    }
}

extern "C" void kernel_launch(void* const* d_in, const int* in_sizes, int n_in,
                              void* d_out, int out_size, void* d_ws, size_t ws_size,
                              hipStream_t stream) {
    const float* x     = (const float*)d_in[0];
    const int*   mask  = (const int*)  d_in[1];
    const float* Wq    = (const float*)d_in[2];
    const float* bq    = (const float*)d_in[3];
    const float* Wk    = (const float*)d_in[4];
    const float* bk    = (const float*)d_in[5];
    const float* Wv    = (const float*)d_in[6];
    const float* bv    = (const float*)d_in[7];
    const float* gamma = (const float*)d_in[8];
    float* outp = (float*)d_out;

    // ws (bf16 shorts): WT 0.75MB | Qh 2MB | Kh 2MB | Vf 8MB
    unsigned short* WT = (unsigned short*)d_ws;
    unsigned short* Qh = WT + (size_t)768*512;
    unsigned short* Kh = Qh + (size_t)8192*128;
    unsigned short* Vf = Kh + (size_t)8192*128;

    wtrans_kernel<<<dim3(12, 8), 256, 0, stream>>>(Wq, Wk, Wv, WT);
    proj_mfma<<<dim3(6, 128), 256, 0, stream>>>(x, WT, bq, bk, bv, Qh, Kh, Vf);
    attn_mfma<<<dim3(32, 32), 512, 0, stream>>>(Qh, Kh, Vf, mask, gamma, outp);
}